// Round 18
// baseline (137.352 us; speedup 1.0000x reference)
//
#include <hip/hip_runtime.h>
#include <stdint.h>

// PressureLSTM: B=4096, T=512, F=32, H=32, gates=128 (i,f,g,o).
// Swapped-MFMA, permuted gate index pg = e*4 + gtype (verified r5-r17):
//   mfma(A=W', B=X^T/H^T); lane's 4 acc regs = i,f,g,o of
//   (element e=4*wv+q, batch row col) -> lane-local cell update.
// r18 (from r17 base = 134.7us):
//   - P=40 -> P=36. P=40 (20 dw, gcd(20,32)=4) aliases the 16 col-strided
//     b128 reads onto 8 bank-quads; P=36 (18 dw, gcd=2) gives 16 distinct
//     bank offsets (18*col mod 32 injective over col<16), rows stay
//     8B-aligned for ds_read_b128. Targets the 1.05e7 bank conflicts
//     (~80 cyc/step-CU).
//   - clamp via one v_med3_f32 (__builtin_amdgcn_fmed3f) on the chain.
//   Everything else identical to r17: 8 waves, 16 real rows, de-burst
//   (axn/a1c/stage after hs write), cs-domain single-rcp activation,
//   xs[4] ring staged 3 ahead, C-operand x-projection, f16 weights
//   pre-scaled -log2e (i,f,o) / +2log2e (g), one __syncthreads per step.

typedef _Float16 half8 __attribute__((ext_vector_type(8)));
typedef __attribute__((ext_vector_type(4))) float float4v;

#define T_LEN 512
#define B_ALL 4096
#define ROWS 16
#define NBLK (B_ALL / ROWS)   // 256 blocks -> 1 block/CU
#define P 36                  // f16 per LDS row (72 B pitch; see header)
#define CLAMP_CS 46.166f      // 16 * 2.88539 (tanh saturates, exp2 safe)

__global__ __launch_bounds__(512, 2) void lstm_fused_kernel(
    const float* __restrict__ x,     // [B, T, 32]
    const float* __restrict__ W_ih,  // [128, 32]
    const float* __restrict__ W_hh,  // [128, 32]
    const float* __restrict__ b_ih,  // [128]
    const float* __restrict__ b_hh,  // [128]
    const float* __restrict__ W_fc,  // [1, 32]
    const float* __restrict__ b_fc,  // [1]
    float* __restrict__ out)         // [B]
{
    const int tid  = threadIdx.x;    // 0..511
    const int wv   = tid >> 6;       // wave 0..7 (gate tile wv)
    const int lane = tid & 63;
    const int col  = lane & 15;      // batch row within tile (all real)
    const int q    = lane >> 4;      // 0..3
    const int k0   = q * 8;
    const int b0   = blockIdx.x * ROWS;
    const int e    = 4 * wv + q;     // this lane's h element (0..31)

    __shared__ __align__(16) _Float16 hs[2][ROWS][P];
    __shared__ __align__(16) _Float16 xs[4][ROWS][P];

    // ---- A-fragment weights, single f16 (RNE), pre-scaled per gate type:
    // lane holds W'[pg=16wv+col][k0..k0+7]; pg=e'*4+gt, e'=4wv+(col>>2), gt=col&3
    half8 wih, whh;
    {
        const int gt   = col & 3;
        const int gmem = gt * 32 + (4 * wv + (col >> 2));
        const float gs = (gt == 2) ? 2.88539008f : -1.44269504f;
        const float* wr = W_ih + gmem * 32 + k0;
        const float* hr = W_hh + gmem * 32 + k0;
        #pragma unroll
        for (int i = 0; i < 8; ++i) {
            wih[i] = (_Float16)(wr[i] * gs);
            whh[i] = (_Float16)(hr[i] * gs);
        }
    }
    // bias for acc reg r: gate type r of element e, same pre-scale
    float4v bias4;
    #pragma unroll
    for (int r = 0; r < 4; ++r) {
        const float gsr = (r == 2) ? 2.88539008f : -1.44269504f;
        bias4[r] = (b_ih[r * 32 + e] + b_hh[r * 32 + e]) * gsr;
    }

    float cs = 0.f;   // cell state in scaled domain: cs = 2*log2e * c

    // ---- x staging: all 512 threads cover 16 rows x 32 k, one float each
    const int sr = tid >> 5;         // staged row 0..15
    const int sk = tid & 31;         // k element
    const float* xsrc = x + ((size_t)(b0 + sr) * T_LEN) * 32 + sk;

    // prologue: prime xs[0..2] with x(0..2); h(-1)=0; FIFO xA=x(3), xB=x(4)
    float xA, xB;
    {
        xs[0][sr][sk] = (_Float16)xsrc[0];
        xs[1][sr][sk] = (_Float16)xsrc[32];
        xs[2][sr][sk] = (_Float16)xsrc[64];
        hs[0][sr][sk] = (_Float16)0.f;
        xA = xsrc[3 * 32];
        xB = xsrc[4 * 32];
    }
    __syncthreads();

    // a1c for t=0 (x-side acc, bias folded as C)
    float4v a1c;
    {
        const half8 ax0 = *(const half8*)&xs[0][col][k0];
        a1c = __builtin_amdgcn_mfma_f32_16x16x32_f16(wih, ax0, bias4, 0, 0, 0);
    }

    // step t (hs parity PPAR=t&1): reads hs[PPAR], writes hs[PPAR^1].
    // Chain: ds_read(ah) -> mfma(whh,ah,C=a1c) -> cs-domain act -> hs write.
    // Off-chain (after hs write): axn read, a1c MFMA, xs stage, x load.
    #define STEP(PPAR, XREG, TT)                                                \
    {                                                                           \
        const half8 ah = *(const half8*)&hs[PPAR][col][k0];   /* critical */    \
        const float4v acc =                                                     \
            __builtin_amdgcn_mfma_f32_16x16x32_f16(whh, ah, a1c, 0, 0, 0);      \
        /* cs-domain fused activations:                                      */ \
        /* cs' = fma(cs, pIG, 2L*(Bg-1)*pF) * rcp(pF*pIG); C2=exp2(med3)    */  \
        const float Ai = __builtin_amdgcn_exp2f(acc[0]);                        \
        const float Af = __builtin_amdgcn_exp2f(acc[1]);                        \
        const float Bg = __builtin_amdgcn_exp2f(acc[2]);                        \
        const float Ao = __builtin_amdgcn_exp2f(acc[3]);                        \
        const float pI = 1.0f + Ai;                                             \
        const float pG = 1.0f + Bg;                                             \
        const float pF = 1.0f + Af;                                             \
        const float pIG = pI * pG;                                              \
        const float t2  = 2.88539008f * (Bg - 1.0f) * pF;                       \
        const float rden = __builtin_amdgcn_rcpf(pF * pIG);                     \
        const float num = __builtin_fmaf(cs, pIG, t2);                          \
        cs = num * rden;                                                        \
        const float ccs = __builtin_amdgcn_fmed3f(cs, -CLAMP_CS, CLAMP_CS);     \
        const float C2 = __builtin_amdgcn_exp2f(ccs);                           \
        const float r3 = __builtin_amdgcn_rcpf((1.0f + Ao) * (1.0f + C2));      \
        const float hv = (C2 - 1.0f) * r3;                                      \
        hs[PPAR ^ 1][col][e] = (_Float16)hv;                                    \
        /* ---- off-chain work (fills write-retire + barrier window) ---- */    \
        const half8 axn = *(const half8*)&xs[((TT) + 1) & 3][col][k0];          \
        a1c = __builtin_amdgcn_mfma_f32_16x16x32_f16(wih, axn, bias4, 0, 0, 0); \
        xs[((TT) + 3) & 3][sr][sk] = (_Float16)XREG;                            \
        {                                                                       \
            int tn = (TT) + 5; if (tn >= T_LEN) tn = T_LEN - 1;                 \
            XREG = xsrc[(size_t)tn * 32];                                       \
        }                                                                       \
        __syncthreads();                                                        \
    }

    for (int t = 0; t < T_LEN; t += 2) {
        STEP(0, xA, t)
        STEP(1, xB, t + 1)
    }
    #undef STEP

    // ---- epilogue: h(511) was written to hs[0] (step 511 has parity 1)
    if (tid < ROWS) {
        float s = b_fc[0];
        #pragma unroll
        for (int cc2 = 0; cc2 < 32; ++cc2) {
            s += (float)hs[0][tid][cc2] * W_fc[cc2];
        }
        out[b0 + tid] = s;
    }
}

extern "C" void kernel_launch(void* const* d_in, const int* in_sizes, int n_in,
                              void* d_out, int out_size, void* d_ws, size_t ws_size,
                              hipStream_t stream) {
    const float* x    = (const float*)d_in[0];
    const float* W_ih = (const float*)d_in[1];
    const float* W_hh = (const float*)d_in[2];
    const float* b_ih = (const float*)d_in[3];
    const float* b_hh = (const float*)d_in[4];
    const float* W_fc = (const float*)d_in[5];
    const float* b_fc = (const float*)d_in[6];
    float* out = (float*)d_out;

    lstm_fused_kernel<<<dim3(NBLK), dim3(512), 0, stream>>>(
        x, W_ih, W_hh, b_ih, b_hh, W_fc, b_fc, out);
}

// Round 19
// 132.555 us; speedup vs baseline: 1.0362x; 1.0362x over previous
//
#include <hip/hip_runtime.h>
#include <stdint.h>

// PressureLSTM: B=4096, T=512, F=32, H=32, gates=128 (i,f,g,o).
// Swapped-MFMA, permuted gate index pg = e*4 + gtype (verified r5-r18):
//   mfma(A=W', B=X^T/H^T); lane's 4 acc regs = i,f,g,o of
//   (element e=4*wv+q, batch row col) -> lane-local cell update.
// r19 (from r17/r18 base = 134.7us):
//   TAIL ELIMINATION: the off-chain block (axn ds_read + a1c MFMA + xs stage
//   + x load) moves from AFTER the hs write (where the barrier's implicit
//   lgkmcnt(0) waited ~130cyc for the axn read = pre-barrier tail) to
//   BETWEEN the critical MFMA and the activation chain, overlapping its
//   latency with the act chain instead of extending the window.
//   xs[(t+1)&3] was written at t-2 -> early read is legal. a1c rotates via
//   a temp. P=36 kept (conflicts measured 0), med3 clamp kept.
//   Everything else identical: 8 waves, 16 real rows, xs[4] ring staged 3
//   ahead, C-operand x-projection, f16 weights pre-scaled -log2e/+2log2e,
//   cs-domain single-rcp activation, one __syncthreads per step.

typedef _Float16 half8 __attribute__((ext_vector_type(8)));
typedef __attribute__((ext_vector_type(4))) float float4v;

#define T_LEN 512
#define B_ALL 4096
#define ROWS 16
#define NBLK (B_ALL / ROWS)   // 256 blocks -> 1 block/CU
#define P 36                  // f16 per LDS row (72 B pitch; 18*col mod 32 injective)
#define CLAMP_CS 46.166f      // 16 * 2.88539 (tanh saturates, exp2 safe)

__global__ __launch_bounds__(512, 2) void lstm_fused_kernel(
    const float* __restrict__ x,     // [B, T, 32]
    const float* __restrict__ W_ih,  // [128, 32]
    const float* __restrict__ W_hh,  // [128, 32]
    const float* __restrict__ b_ih,  // [128]
    const float* __restrict__ b_hh,  // [128]
    const float* __restrict__ W_fc,  // [1, 32]
    const float* __restrict__ b_fc,  // [1]
    float* __restrict__ out)         // [B]
{
    const int tid  = threadIdx.x;    // 0..511
    const int wv   = tid >> 6;       // wave 0..7 (gate tile wv)
    const int lane = tid & 63;
    const int col  = lane & 15;      // batch row within tile (all real)
    const int q    = lane >> 4;      // 0..3
    const int k0   = q * 8;
    const int b0   = blockIdx.x * ROWS;
    const int e    = 4 * wv + q;     // this lane's h element (0..31)

    __shared__ __align__(16) _Float16 hs[2][ROWS][P];
    __shared__ __align__(16) _Float16 xs[4][ROWS][P];

    // ---- A-fragment weights, single f16 (RNE), pre-scaled per gate type:
    // lane holds W'[pg=16wv+col][k0..k0+7]; pg=e'*4+gt, e'=4wv+(col>>2), gt=col&3
    half8 wih, whh;
    {
        const int gt   = col & 3;
        const int gmem = gt * 32 + (4 * wv + (col >> 2));
        const float gs = (gt == 2) ? 2.88539008f : -1.44269504f;
        const float* wr = W_ih + gmem * 32 + k0;
        const float* hr = W_hh + gmem * 32 + k0;
        #pragma unroll
        for (int i = 0; i < 8; ++i) {
            wih[i] = (_Float16)(wr[i] * gs);
            whh[i] = (_Float16)(hr[i] * gs);
        }
    }
    // bias for acc reg r: gate type r of element e, same pre-scale
    float4v bias4;
    #pragma unroll
    for (int r = 0; r < 4; ++r) {
        const float gsr = (r == 2) ? 2.88539008f : -1.44269504f;
        bias4[r] = (b_ih[r * 32 + e] + b_hh[r * 32 + e]) * gsr;
    }

    float cs = 0.f;   // cell state in scaled domain: cs = 2*log2e * c

    // ---- x staging: all 512 threads cover 16 rows x 32 k, one float each
    const int sr = tid >> 5;         // staged row 0..15
    const int sk = tid & 31;         // k element
    const float* xsrc = x + ((size_t)(b0 + sr) * T_LEN) * 32 + sk;

    // prologue: prime xs[0..2] with x(0..2); h(-1)=0; FIFO xA=x(3), xB=x(4)
    float xA, xB;
    {
        xs[0][sr][sk] = (_Float16)xsrc[0];
        xs[1][sr][sk] = (_Float16)xsrc[32];
        xs[2][sr][sk] = (_Float16)xsrc[64];
        hs[0][sr][sk] = (_Float16)0.f;
        xA = xsrc[3 * 32];
        xB = xsrc[4 * 32];
    }
    __syncthreads();

    // a1c for t=0 (x-side acc, bias folded as C)
    float4v a1c;
    {
        const half8 ax0 = *(const half8*)&xs[0][col][k0];
        a1c = __builtin_amdgcn_mfma_f32_16x16x32_f16(wih, ax0, bias4, 0, 0, 0);
    }

    // step t (hs parity PPAR=t&1): reads hs[PPAR], writes hs[PPAR^1].
    // Window: ds_read(ah) -> crit MFMA -> [independent block issues here:
    // axn read, a1c_next MFMA, xs stage, x load -- latency overlaps the act
    // chain] -> cs-domain act -> hs write -> barrier (tail ~= write only).
    #define STEP(PPAR, XREG, TT)                                                \
    {                                                                           \
        const half8 ah = *(const half8*)&hs[PPAR][col][k0];   /* critical */    \
        const float4v acc =                                                     \
            __builtin_amdgcn_mfma_f32_16x16x32_f16(whh, ah, a1c, 0, 0, 0);      \
        /* independent block: overlapped with act chain, not the tail */        \
        const half8 axn = *(const half8*)&xs[((TT) + 1) & 3][col][k0];          \
        const float4v a1n =                                                     \
            __builtin_amdgcn_mfma_f32_16x16x32_f16(wih, axn, bias4, 0, 0, 0);   \
        xs[((TT) + 3) & 3][sr][sk] = (_Float16)XREG;                            \
        {                                                                       \
            int tn = (TT) + 5; if (tn >= T_LEN) tn = T_LEN - 1;                 \
            XREG = xsrc[(size_t)tn * 32];                                       \
        }                                                                       \
        /* cs-domain fused activations:                                      */ \
        /* cs' = fma(cs, pIG, 2L*(Bg-1)*pF) * rcp(pF*pIG); C2=exp2(med3)    */  \
        const float Ai = __builtin_amdgcn_exp2f(acc[0]);                        \
        const float Af = __builtin_amdgcn_exp2f(acc[1]);                        \
        const float Bg = __builtin_amdgcn_exp2f(acc[2]);                        \
        const float Ao = __builtin_amdgcn_exp2f(acc[3]);                        \
        const float pI = 1.0f + Ai;                                             \
        const float pG = 1.0f + Bg;                                             \
        const float pF = 1.0f + Af;                                             \
        const float pIG = pI * pG;                                              \
        const float t2  = 2.88539008f * (Bg - 1.0f) * pF;                       \
        const float rden = __builtin_amdgcn_rcpf(pF * pIG);                     \
        const float num = __builtin_fmaf(cs, pIG, t2);                          \
        cs = num * rden;                                                        \
        const float ccs = __builtin_amdgcn_fmed3f(cs, -CLAMP_CS, CLAMP_CS);     \
        const float C2 = __builtin_amdgcn_exp2f(ccs);                           \
        const float r3 = __builtin_amdgcn_rcpf((1.0f + Ao) * (1.0f + C2));      \
        const float hv = (C2 - 1.0f) * r3;                                      \
        hs[PPAR ^ 1][col][e] = (_Float16)hv;                                    \
        a1c = a1n;                                                              \
        __syncthreads();                                                        \
    }

    for (int t = 0; t < T_LEN; t += 2) {
        STEP(0, xA, t)
        STEP(1, xB, t + 1)
    }
    #undef STEP

    // ---- epilogue: h(511) was written to hs[0] (step 511 has parity 1)
    if (tid < ROWS) {
        float s = b_fc[0];
        #pragma unroll
        for (int cc2 = 0; cc2 < 32; ++cc2) {
            s += (float)hs[0][tid][cc2] * W_fc[cc2];
        }
        out[b0 + tid] = s;
    }
}

extern "C" void kernel_launch(void* const* d_in, const int* in_sizes, int n_in,
                              void* d_out, int out_size, void* d_ws, size_t ws_size,
                              hipStream_t stream) {
    const float* x    = (const float*)d_in[0];
    const float* W_ih = (const float*)d_in[1];
    const float* W_hh = (const float*)d_in[2];
    const float* b_ih = (const float*)d_in[3];
    const float* b_hh = (const float*)d_in[4];
    const float* W_fc = (const float*)d_in[5];
    const float* b_fc = (const float*)d_in[6];
    float* out = (float*)d_out;

    lstm_fused_kernel<<<dim3(NBLK), dim3(512), 0, stream>>>(
        x, W_ih, W_hh, b_ih, b_hh, W_fc, b_fc, out);
}